// Round 2
// baseline (42675.589 us; speedup 1.0000x reference)
//
#include <hip/hip_runtime.h>

// DeepAR MI355X round 2: single persistent kernel, weights LDS-resident,
// flag-based (no grid.sync) producer/consumer pipelining across 160 steps.
// B=128, T=160, F=512, E=64, H=1024, L=2. Output [B,T,2] fp32.
//
// Partition: 256 WGs (1/CU, LDS-bound), WG blk owns 16 gate-cols = hidden
// units blk*4..blk*4+3 for BOTH layers; all 128 batch rows. 512 thr = 8 waves,
// wave w computes M-tile w (rows 16w..16w+15) x N=16 cols via 16x16x32 bf16 MFMA.
// Packed col c = 4*j+q  <->  original gate row q*1024 + blk*4 + j.
//
// Sync: monotonic agent-scope counters. Per step:
//   A-head : wait doneB>=256t  -> reduce partials(t-1), publish muf/out, doneA++
//   A-mid  : feat+h0 GEMM, wait doneA>=256t, lab build, lab GEMM, cell0
//   A-tail : publish h0(pc)+partials, doneH0++
//   B      : h1(pp) GEMM, wait doneH0>=256(t+1), h0(pc) GEMM, cell1,
//            publish h1(pc)+partials, doneB++
// Skew between WGs is bounded to <1 step by the wait chain => 2-parity buffers.

#define B_  128
#define T_  160
#define FD  512
#define E_  64
#define H_  1024
#define NT  512

typedef unsigned short u16;
typedef __attribute__((ext_vector_type(8))) short bf16x8;
typedef __attribute__((ext_vector_type(4))) float f32x4;

__device__ __forceinline__ bf16x8 ld8(const u16* p) {
    return *reinterpret_cast<const bf16x8*>(p);
}
__device__ __forceinline__ f32x4 mfma16(bf16x8 a, bf16x8 b, f32x4 c) {
    return __builtin_amdgcn_mfma_f32_16x16x32_bf16(a, b, c, 0, 0, 0);
}
__device__ __forceinline__ u16 f2bf(float x) {
    unsigned u = __float_as_uint(x);
    u += 0x7FFFu + ((u >> 16) & 1u);   // RNE
    return (u16)(u >> 16);
}
__device__ __forceinline__ float sigm(float x)  { return 1.f / (1.f + __expf(-x)); }
__device__ __forceinline__ float tanh_(float x) { return 1.f - 2.f / (__expf(2.f * x) + 1.f); }
__device__ __forceinline__ float softp(float x) { return x > 20.f ? x : log1pf(__expf(x)); }

__device__ __forceinline__ unsigned ldctr(const unsigned* p) {
    return __hip_atomic_load(p, __ATOMIC_RELAXED, __HIP_MEMORY_SCOPE_AGENT);
}
__device__ __forceinline__ void addctr(unsigned* p) {
    __hip_atomic_fetch_add(p, 1u, __ATOMIC_RELAXED, __HIP_MEMORY_SCOPE_AGENT);
}

// ---------------- prologue kernels ----------------

__global__ void detect_mask(const unsigned* __restrict__ m, int* __restrict__ flags) {
    int i = blockIdx.x * 256 + threadIdx.x;   // first 5120 words, safe in all interps
    unsigned w = m[i];
    if (w > 1u) atomicOr(&flags[0], 1);
    if (w != 0u && w != 0x3F800000u) atomicOr(&flags[1], 1);
}

// feat [B][T][512] fp32 -> fb [T][B][512] bf16
__global__ void featconv(const float* __restrict__ feat, u16* __restrict__ fb) {
    int i = blockIdx.x * 256 + threadIdx.x;   // [0, 160*128*128) float4 units
    int kv = i & 127;
    int b  = (i >> 7) & 127;
    int t  = i >> 14;
    float4 v = reinterpret_cast<const float4*>(feat)[((size_t)(b * T_ + t)) * 128 + kv];
    ushort4 o = make_ushort4(f2bf(v.x), f2bf(v.y), f2bf(v.z), f2bf(v.w));
    reinterpret_cast<ushort4*>(fb)[((size_t)(t * B_ + b)) * 128 + kv] = o;
}

// ---------------- persistent kernel ----------------

struct SMem {
    u16   b0[50 * 512];    // [chunk][pr16][k32]  51200 B  (feat 0-15, lab 16-17, h0 18-49)
    u16   b1[64 * 512];    // [chunk][pr16][k32]  65536 B  (h0 0-31, h1 32-63)
    u16   lab[128 * 72];   // label tile, 72-short rows (16B-aligned, bank-spread)
    float gt[128 * 17];    // gate pre-activations
    float mu_s[128];
    float wt[64], bt[64];
    float bias0[16], bias1[16];
    float mw0[4], sw0[4], mw1[4], sw1[4];
    float red[8];
};

__global__ void __launch_bounds__(NT, 2) persist(
    const u16* __restrict__ fb, const float* __restrict__ emb,
    const void* __restrict__ mask, const int* __restrict__ flags,
    const float* __restrict__ Wih0, const float* __restrict__ Whh0,
    const float* __restrict__ bih0, const float* __restrict__ bhh0,
    const float* __restrict__ Wih1, const float* __restrict__ Whh1,
    const float* __restrict__ bih1, const float* __restrict__ bhh1,
    const float* __restrict__ Wtgt, const float* __restrict__ btgt,
    const float* __restrict__ muw, const float* __restrict__ mubp,
    const float* __restrict__ sgw, const float* __restrict__ sgbp,
    float* __restrict__ c0, float* __restrict__ c1,
    u16* __restrict__ h0b, u16* __restrict__ h1b,
    float* __restrict__ pA, float* __restrict__ pB,
    float* __restrict__ muf, unsigned* __restrict__ ctrs,
    float* __restrict__ out)
{
    __shared__ SMem sm;
    const int tid  = threadIdx.x;
    const int blk  = blockIdx.x;
    const int w    = tid >> 6;
    const int lane = tid & 63;
    const int quad = lane >> 4;
    const int l16  = lane & 15;
    const int ko   = quad * 8;
    const int rowA = w * 16 + l16;         // this wave's A-row

    unsigned* doneA  = ctrs + 0;
    unsigned* doneH0 = ctrs + 32;
    unsigned* doneB  = ctrs + 64;

    // ---- one-time init: pack weights into LDS ----
    for (int i = tid; i < 16 * 1600; i += NT) {
        int pr = i / 1600, k = i - pr * 1600;
        int q = pr & 3, j = pr >> 2;
        int row = q * 1024 + blk * 4 + j;
        float v = (k < 576) ? Wih0[row * 576 + k] : Whh0[row * 1024 + (k - 576)];
        sm.b0[(k >> 5) * 512 + pr * 32 + (k & 31)] = f2bf(v);
    }
    for (int i = tid; i < 16 * 2048; i += NT) {
        int pr = i >> 11, k = i & 2047;
        int q = pr & 3, j = pr >> 2;
        int row = q * 1024 + blk * 4 + j;
        float v = (k < 1024) ? Wih1[row * 1024 + k] : Whh1[row * 1024 + (k - 1024)];
        sm.b1[(k >> 5) * 512 + pr * 32 + (k & 31)] = f2bf(v);
    }
    if (tid < 64) { sm.wt[tid] = Wtgt[tid]; sm.bt[tid] = btgt[tid]; }
    if (tid < 16) {
        int q = tid & 3, j = tid >> 2, row = q * 1024 + blk * 4 + j;
        sm.bias0[tid] = bih0[row] + bhh0[row];
        sm.bias1[tid] = bih1[row] + bhh1[row];
    }
    if (tid < 4) {
        int h = blk * 4 + tid;
        sm.mw0[tid] = muw[2 * h];     sm.sw0[tid] = sgw[2 * h];
        sm.mw1[tid] = muw[2 * h + 1]; sm.sw1[tid] = sgw[2 * h + 1];
    }
    const int nonbin = flags[0], nonfl = flags[1];
    __syncthreads();

    const int ob = blk >> 1, owhich = blk & 1;   // every WG owns (batch ob, mu|sigma)

    for (int t = 0; t < T_; ++t) {
        const int pc = t & 1, pp = pc ^ 1;
        const u16* h0r = h0b + pp * (B_ * H_);
        u16*       h0w = h0b + pc * (B_ * H_);
        const u16* h1r = h1b + pp * (B_ * H_);
        u16*       h1w = h1b + pc * (B_ * H_);

        // ===================== phase A =====================
        if (t > 0) {
            // wait for B(t-1) tails (partials + h1 published)
            if (tid == 0) { unsigned tgt = 256u * (unsigned)t; while (ldctr(doneB) < tgt) {} }
            __syncthreads();
            __threadfence();
            // owner-reduce partials of step t-1 (parity pp), publish muf + out
            float val = 0.f;
            if (tid < 256) {
                int idx = ((pp * B_ + ob) * 256 + tid) * 2 + owhich;
                val = pA[idx] + pB[idx];
            }
            #pragma unroll
            for (int off = 1; off < 64; off <<= 1) val += __shfl_xor(val, off);
            if (tid < 256 && lane == 0) sm.red[w] = val;
            __syncthreads();
            if (tid == 0) {
                float tot = sm.red[0] + sm.red[1] + sm.red[2] + sm.red[3];
                if (owhich == 0) {
                    float m = tot + mubp[0];
                    muf[pc * B_ + ob] = m;
                    out[(ob * T_ + (t - 1)) * 2 + 0] = m;
                } else {
                    out[(ob * T_ + (t - 1)) * 2 + 1] = softp(tot + sgbp[0]);
                }
                __threadfence();
                addctr(doneA);
            }
        }

        // ---- GEMM part 1: feat chunks (0..15) + h0 chunks (18..49) ----
        f32x4 acc0 = {0.f, 0.f, 0.f, 0.f};
        f32x4 acc1 = {0.f, 0.f, 0.f, 0.f};
        {
            const u16* aF = fb + ((size_t)(t * B_ + rowA)) * FD + ko;
            #pragma unroll
            for (int kc = 0; kc < 16; ++kc) {
                bf16x8 bfr = *(const bf16x8*)&sm.b0[kc * 512 + l16 * 32 + ko];
                bf16x8 a = ld8(aF + kc * 32);
                if (kc & 1) acc1 = mfma16(a, bfr, acc1);
                else        acc0 = mfma16(a, bfr, acc0);
            }
        }
        if (t > 0) {
            const u16* aH = h0r + (size_t)rowA * H_ + ko;
            #pragma unroll 8
            for (int kc = 0; kc < 32; ++kc) {
                bf16x8 bfr = *(const bf16x8*)&sm.b0[(18 + kc) * 512 + l16 * 32 + ko];
                bf16x8 a = ld8(aH + kc * 32);
                if (kc & 1) acc1 = mfma16(a, bfr, acc1);
                else        acc0 = mfma16(a, bfr, acc0);
            }
        }

        // ---- wait for all mu publications, build label tile ----
        if (t > 0) {
            if (tid == 0) { unsigned tgt = 256u * (unsigned)t; while (ldctr(doneA) < tgt) {} }
            __syncthreads();
            __threadfence();
            if (tid < B_) sm.mu_s[tid] = muf[pc * B_ + tid];
            __syncthreads();
        }
        for (int i = tid; i < B_ * E_; i += NT) {
            int b = i >> 6, e = i & 63;
            bool um = false;
            if (t > 0) {
                int mi = b * T_ + t;
                um = !nonbin ? (reinterpret_cast<const int*>(mask)[mi] != 0)
                   : !nonfl  ? (reinterpret_cast<const float*>(mask)[mi] != 0.f)
                             : (reinterpret_cast<const unsigned char*>(mask)[mi] != 0);
            }
            float v = um ? (sm.mu_s[b] * sm.wt[e] + sm.bt[e])
                         : emb[((size_t)b * T_ + t) * E_ + e];
            sm.lab[b * 72 + e] = f2bf(v);
        }
        __syncthreads();
        #pragma unroll
        for (int kc = 0; kc < 2; ++kc) {
            bf16x8 bfr = *(const bf16x8*)&sm.b0[(16 + kc) * 512 + l16 * 32 + ko];
            bf16x8 a = *(const bf16x8*)&sm.lab[rowA * 72 + kc * 32 + ko];
            if (kc & 1) acc1 = mfma16(a, bfr, acc1);
            else        acc0 = mfma16(a, bfr, acc0);
        }
        {
            f32x4 acc = acc0 + acc1;
            int rl = w * 16 + quad * 4;      // C/D: col=lane&15, row=quad*4+reg
            #pragma unroll
            for (int r = 0; r < 4; ++r) sm.gt[(rl + r) * 17 + l16] = acc[r];
        }
        __syncthreads();

        // ---- cell0 update: task tid -> (b = tid>>2, j = tid&3) ----
        {
            int b = tid >> 2, j = tid & 3;
            int h = blk * 4 + j;
            float gi = sm.gt[b * 17 + 4 * j + 0] + sm.bias0[4 * j + 0];
            float gf = sm.gt[b * 17 + 4 * j + 1] + sm.bias0[4 * j + 1];
            float gg = sm.gt[b * 17 + 4 * j + 2] + sm.bias0[4 * j + 2];
            float go = sm.gt[b * 17 + 4 * j + 3] + sm.bias0[4 * j + 3];
            float cold = c0[(size_t)b * H_ + h];
            float cn = sigm(gf) * cold + sigm(gi) * tanh_(gg);
            float hn = sigm(go) * tanh_(cn);
            c0[(size_t)b * H_ + h] = cn;
            h0w[(size_t)b * H_ + h] = f2bf(hn);
            float pmu = hn * sm.mw0[j], psg = hn * sm.sw0[j];
            pmu += __shfl_xor(pmu, 1); pmu += __shfl_xor(pmu, 2);
            psg += __shfl_xor(psg, 1); psg += __shfl_xor(psg, 2);
            if (j == 0) {
                int idx = ((pc * B_ + b) * 256 + blk) * 2;
                pA[idx] = pmu; pA[idx + 1] = psg;
            }
        }
        __threadfence();
        __syncthreads();
        if (tid == 0) addctr(doneH0);

        // ===================== phase B =====================
        f32x4 bacc0 = {0.f, 0.f, 0.f, 0.f};
        f32x4 bacc1 = {0.f, 0.f, 0.f, 0.f};
        if (t > 0) {   // h1(t-1) chunks first — independent of doneH0
            const u16* aH1 = h1r + (size_t)rowA * H_ + ko;
            #pragma unroll 8
            for (int kc = 0; kc < 32; ++kc) {
                bf16x8 bfr = *(const bf16x8*)&sm.b1[(32 + kc) * 512 + l16 * 32 + ko];
                bf16x8 a = ld8(aH1 + kc * 32);
                if (kc & 1) bacc1 = mfma16(a, bfr, bacc1);
                else        bacc0 = mfma16(a, bfr, bacc0);
            }
        }
        if (tid == 0) { unsigned tgt = 256u * (unsigned)(t + 1); while (ldctr(doneH0) < tgt) {} }
        __syncthreads();
        __threadfence();
        {
            const u16* aH0 = h0b + pc * (B_ * H_) + (size_t)rowA * H_ + ko;
            #pragma unroll 8
            for (int kc = 0; kc < 32; ++kc) {
                bf16x8 bfr = *(const bf16x8*)&sm.b1[kc * 512 + l16 * 32 + ko];
                bf16x8 a = ld8(aH0 + kc * 32);
                if (kc & 1) bacc1 = mfma16(a, bfr, bacc1);
                else        bacc0 = mfma16(a, bfr, bacc0);
            }
        }
        {
            f32x4 acc = bacc0 + bacc1;
            int rl = w * 16 + quad * 4;
            #pragma unroll
            for (int r = 0; r < 4; ++r) sm.gt[(rl + r) * 17 + l16] = acc[r];
        }
        __syncthreads();
        {
            int b = tid >> 2, j = tid & 3;
            int h = blk * 4 + j;
            float gi = sm.gt[b * 17 + 4 * j + 0] + sm.bias1[4 * j + 0];
            float gf = sm.gt[b * 17 + 4 * j + 1] + sm.bias1[4 * j + 1];
            float gg = sm.gt[b * 17 + 4 * j + 2] + sm.bias1[4 * j + 2];
            float go = sm.gt[b * 17 + 4 * j + 3] + sm.bias1[4 * j + 3];
            float cold = c1[(size_t)b * H_ + h];
            float cn = sigm(gf) * cold + sigm(gi) * tanh_(gg);
            float hn = sigm(go) * tanh_(cn);
            c1[(size_t)b * H_ + h] = cn;
            h1w[(size_t)b * H_ + h] = f2bf(hn);
            float pmu = hn * sm.mw1[j], psg = hn * sm.sw1[j];
            pmu += __shfl_xor(pmu, 1); pmu += __shfl_xor(pmu, 2);
            psg += __shfl_xor(psg, 1); psg += __shfl_xor(psg, 2);
            if (j == 0) {
                int idx = ((pc * B_ + b) * 256 + blk) * 2;
                pB[idx] = pmu; pB[idx + 1] = psg;
            }
        }
        __threadfence();
        __syncthreads();
        if (tid == 0) addctr(doneB);
    }

    // ---- final output for t = T_-1 (parity 1) ----
    if (tid == 0) { unsigned tgt = 256u * (unsigned)T_; while (ldctr(doneB) < tgt) {} }
    __syncthreads();
    __threadfence();
    {
        float val = 0.f;
        if (tid < 256) {
            int idx = ((1 * B_ + ob) * 256 + tid) * 2 + owhich;
            val = pA[idx] + pB[idx];
        }
        #pragma unroll
        for (int off = 1; off < 64; off <<= 1) val += __shfl_xor(val, off);
        if (tid < 256 && lane == 0) sm.red[w] = val;
        __syncthreads();
        if (tid == 0) {
            float tot = sm.red[0] + sm.red[1] + sm.red[2] + sm.red[3];
            if (owhich == 0) out[(ob * T_ + (T_ - 1)) * 2 + 0] = tot + mubp[0];
            else             out[(ob * T_ + (T_ - 1)) * 2 + 1] = softp(tot + sgbp[0]);
        }
    }
}

// ---------------- host ----------------

extern "C" void kernel_launch(void* const* d_in, const int* in_sizes, int n_in,
                              void* d_out, int out_size, void* d_ws, size_t ws_size,
                              hipStream_t stream) {
    const float* feat = (const float*)d_in[0];
    const float* emb  = (const float*)d_in[1];
    const void*  mask = d_in[2];
    const float* Wih0 = (const float*)d_in[3];
    const float* Whh0 = (const float*)d_in[4];
    const float* bih0 = (const float*)d_in[5];
    const float* bhh0 = (const float*)d_in[6];
    const float* Wih1 = (const float*)d_in[7];
    const float* Whh1 = (const float*)d_in[8];
    const float* bih1 = (const float*)d_in[9];
    const float* bhh1 = (const float*)d_in[10];
    const float* Wtgt = (const float*)d_in[11];
    const float* btgt = (const float*)d_in[12];
    const float* muw  = (const float*)d_in[13];
    const float* mub  = (const float*)d_in[14];
    const float* sgw  = (const float*)d_in[15];
    const float* sgb  = (const float*)d_in[16];
    float* out = (float*)d_out;
    char* ws = (char*)d_ws;
    (void)in_sizes; (void)n_in; (void)out_size; (void)ws_size;

    size_t off = 0;
    auto alloc = [&](size_t bytes) {
        size_t o = off;
        off = (off + bytes + 255) & ~(size_t)255;
        return o;
    };
    size_t o_flags = alloc(256);
    size_t o_ctrs  = alloc(512);
    size_t o_c0    = alloc((size_t)B_ * H_ * 4);
    size_t o_c1    = alloc((size_t)B_ * H_ * 4);
    size_t zero_end = off;
    size_t o_h0    = alloc((size_t)2 * B_ * H_ * 2);
    size_t o_h1    = alloc((size_t)2 * B_ * H_ * 2);
    size_t o_pA    = alloc((size_t)2 * B_ * 256 * 2 * 4);
    size_t o_pB    = alloc((size_t)2 * B_ * 256 * 2 * 4);
    size_t o_muf   = alloc((size_t)2 * B_ * 4);
    size_t o_fb    = alloc((size_t)T_ * B_ * FD * 2);

    int*      flags = (int*)(ws + o_flags);
    unsigned* ctrs  = (unsigned*)(ws + o_ctrs);
    float*    c0    = (float*)(ws + o_c0);
    float*    c1    = (float*)(ws + o_c1);
    u16*      h0    = (u16*)(ws + o_h0);
    u16*      h1    = (u16*)(ws + o_h1);
    float*    pA    = (float*)(ws + o_pA);
    float*    pB    = (float*)(ws + o_pB);
    float*    muf   = (float*)(ws + o_muf);
    u16*      fb    = (u16*)(ws + o_fb);

    hipMemsetAsync(ws, 0, zero_end, stream);
    detect_mask<<<20, 256, 0, stream>>>((const unsigned*)mask, flags);
    featconv<<<10240, 256, 0, stream>>>(feat, fb);

    persist<<<256, NT, 0, stream>>>(
        fb, emb, mask, flags,
        Wih0, Whh0, bih0, bhh0,
        Wih1, Whh1, bih1, bhh1,
        Wtgt, btgt, muw, mub, sgw, sgb,
        c0, c1, h0, h1, pA, pB, muf, ctrs, out);
}

// Round 3
// 11965.774 us; speedup vs baseline: 3.5665x; 3.5665x over previous
//
#include <hip/hip_runtime.h>

// DeepAR MI355X round 3: persistent kernel, layer-split workgroups,
// LDS-resident weights (conflict-free MFMA fragment layout), 2 global
// barriers/step with correct release(wbL2)/acquire(inv) semantics.
// B=128, T=160, F=512, E=64, H=1024, L=2. Output [B,T,2] fp32.
//
// WGs 0..127   : layer 0, packed gate cols g*32..g*32+31 (hidden g*8..g*8+7), M=128.
// WGs 128..255 : layer 1, same col ownership for W1.
// Step t windows (separated by grid barriers):
//   W1: L0: read muacc(t-1)->out+label, GEMM lab+h0prev (feat acc carried in),
//       cell0, publish h0(t), atomicAdd mu/sg partials.
//       L1: GEMM h1prev chunks.                     == barrier ==
//   W2: L0: pre-GEMM feat(t+1).  L1: zero old muacc slot, GEMM h0(t) chunks,
//       cell1, publish h1(t), atomicAdd partials.   == barrier ==

#define B_   128
#define T_   160
#define FD   512
#define E_   64
#define H_   1024
#define NT   512
#define NBLK 256
#define BH   (B_ * H_)

typedef unsigned short u16;
typedef __attribute__((ext_vector_type(8))) short bf16x8;
typedef __attribute__((ext_vector_type(4))) float f32x4;

__device__ __forceinline__ bf16x8 ld8(const u16* p) {
    return *reinterpret_cast<const bf16x8*>(p);
}
__device__ __forceinline__ f32x4 mfma16(bf16x8 a, bf16x8 b, f32x4 c) {
    return __builtin_amdgcn_mfma_f32_16x16x32_bf16(a, b, c, 0, 0, 0);
}
__device__ __forceinline__ u16 f2bf(float x) {
    unsigned u = __float_as_uint(x);
    u += 0x7FFFu + ((u >> 16) & 1u);   // RNE
    return (u16)(u >> 16);
}
__device__ __forceinline__ float sigm(float x)  { return 1.f / (1.f + __expf(-x)); }
__device__ __forceinline__ float tanh_(float x) { return 1.f - 2.f / (__expf(2.f * x) + 1.f); }
__device__ __forceinline__ float softp(float x) { return x > 20.f ? x : log1pf(__expf(x)); }

// Grid barrier: release-RMW arrival (flushes L2 via wbl2), acquire-load poll
// (coherence-point read + inv). Monotonic target, one counter.
__device__ __forceinline__ void gbar(unsigned* ctr, unsigned tgt) {
    __syncthreads();
    if (threadIdx.x == 0) {
        __hip_atomic_fetch_add(ctr, 1u, __ATOMIC_RELEASE, __HIP_MEMORY_SCOPE_AGENT);
        while (__hip_atomic_load(ctr, __ATOMIC_ACQUIRE, __HIP_MEMORY_SCOPE_AGENT) < tgt)
            __builtin_amdgcn_s_sleep(1);
    }
    __syncthreads();
}

// ---------------- prologue kernels ----------------

__global__ void detect_mask(const unsigned* __restrict__ m, int* __restrict__ flags) {
    int i = blockIdx.x * 256 + threadIdx.x;   // first 5120 words, safe in all interps
    unsigned w = m[i];
    if (w > 1u) atomicOr(&flags[0], 1);
    if (w != 0u && w != 0x3F800000u) atomicOr(&flags[1], 1);
}

// feat [B][T][512] fp32 -> fb [T][B][512] bf16
__global__ void featconv(const float* __restrict__ feat, u16* __restrict__ fb) {
    int i = blockIdx.x * 256 + threadIdx.x;   // [0, 160*128*128) float4 units
    int kv = i & 127;
    int b  = (i >> 7) & 127;
    int t  = i >> 14;
    float4 v = reinterpret_cast<const float4*>(feat)[((size_t)(b * T_ + t)) * 128 + kv];
    ushort4 o = make_ushort4(f2bf(v.x), f2bf(v.y), f2bf(v.z), f2bf(v.w));
    reinterpret_cast<ushort4*>(fb)[((size_t)(t * B_ + b)) * 128 + kv] = o;
}

// ---------------- persistent kernel ----------------

struct SM0 {                       // layer-0 WGs
    u16   b0[50 * 1024];           // frag-linear: ((c*2+f)*64 + lane)*8 + jj
    u16   lab[128 * 72];           // label tile (pad 72 keeps rows 16B-aligned)
    float gt[128 * 33];
    float mu_s[128];
    unsigned char msk[128];
    float wt[64], bt[64];
    float bias0[32];
    float mw0[8], sw0[8];
    float mubias, sgbias;
};
struct SM1 {                       // layer-1 WGs
    u16   b1[64 * 1024];
    float gt[128 * 33];
    float bias1[32];
    float mw1[8], sw1[8];
};
union SMU { SM0 a; SM1 b; };

__global__ void __launch_bounds__(NT, 2) persist(
    const u16* __restrict__ fb, const float* __restrict__ emb,
    const void* __restrict__ mask, const int* __restrict__ flags,
    const float* __restrict__ Wih0, const float* __restrict__ Whh0,
    const float* __restrict__ bih0, const float* __restrict__ bhh0,
    const float* __restrict__ Wih1, const float* __restrict__ Whh1,
    const float* __restrict__ bih1, const float* __restrict__ bhh1,
    const float* __restrict__ Wtgt, const float* __restrict__ btgt,
    const float* __restrict__ muw, const float* __restrict__ mubp,
    const float* __restrict__ sgw, const float* __restrict__ sgbp,
    u16* __restrict__ h0b, u16* __restrict__ h1b,
    float* __restrict__ muacc, float* __restrict__ sgacc,
    unsigned* __restrict__ ctr, float* __restrict__ out)
{
    __shared__ SMU smu;
    const int tid  = threadIdx.x;
    const int blk  = blockIdx.x;
    const bool isL0 = blk < 128;
    const int g    = isL0 ? blk : blk - 128;   // col-group: hidden units g*8..g*8+7
    const int w    = tid >> 6;
    const int lane = tid & 63;
    const int quad = lane >> 4;
    const int l16  = lane & 15;
    const int ko   = quad * 8;
    const int rowA = w * 16 + l16;             // this wave's A-row (M=128, 8 waves)

    // ---- one-time init: pack this WG's weight slice into LDS ----
    if (isL0) {
        SM0& s0 = smu.a;
        for (int i = tid; i < 32 * 1600; i += NT) {
            int col = i / 1600;
            int k   = i - col * 1600;
            int q = col & 3, j = col >> 2;
            int row = q * H_ + g * 8 + j;
            float v = (k < 576) ? Wih0[row * 576 + k]
                                : Whh0[(size_t)row * H_ + (k - 576)];
            int c = k >> 5, q8 = (k >> 3) & 3, jj = k & 7;
            int f = col >> 4, l = col & 15;
            s0.b0[((c * 2 + f) * 64 + q8 * 16 + l) * 8 + jj] = f2bf(v);
        }
        if (tid < 64) { s0.wt[tid] = Wtgt[tid]; s0.bt[tid] = btgt[tid]; }
        if (tid < 32) {
            int q = tid & 3, j = tid >> 2, row = q * H_ + g * 8 + j;
            s0.bias0[tid] = bih0[row] + bhh0[row];
        }
        if (tid < 8) {
            int h = g * 8 + tid;
            s0.mw0[tid] = muw[2 * h]; s0.sw0[tid] = sgw[2 * h];
        }
        if (tid == 0) { s0.mubias = mubp[0]; s0.sgbias = sgbp[0]; }
    } else {
        SM1& s1 = smu.b;
        for (int i = tid; i < 32 * 2048; i += NT) {
            int col = i >> 11, k = i & 2047;
            int q = col & 3, j = col >> 2;
            int row = q * H_ + g * 8 + j;
            float v = (k < 1024) ? Wih1[(size_t)row * H_ + k]
                                 : Whh1[(size_t)row * H_ + (k - 1024)];
            int c = k >> 5, q8 = (k >> 3) & 3, jj = k & 7;
            int f = col >> 4, l = col & 15;
            s1.b1[((c * 2 + f) * 64 + q8 * 16 + l) * 8 + jj] = f2bf(v);
        }
        if (tid < 32) {
            int q = tid & 3, j = tid >> 2, row = q * H_ + g * 8 + j;
            s1.bias1[tid] = bih1[row] + bhh1[row];
        }
        if (tid < 8) {
            int h = g * 8 + tid;
            s1.mw1[tid] = muw[2 * h + 1]; s1.sw1[tid] = sgw[2 * h + 1];
        }
    }
    const int nonbin = flags[0], nonfl = flags[1];
    __syncthreads();

    float creg0 = 0.f, creg1 = 0.f;            // per-thread cell state (fixed (b,j))
    f32x4 facc0 = {0,0,0,0}, facc1 = {0,0,0,0};
    f32x4 acc0, acc1;

    // feat GEMM for t=0 (L0 only)
    if (isL0) {
        SM0& s0 = smu.a;
        const u16* aF = fb + ((size_t)(0 * B_ + rowA)) * FD + ko;
        #pragma unroll
        for (int c = 0; c < 16; ++c) {
            bf16x8 a = ld8(aF + c * 32);
            facc0 = mfma16(a, *(const bf16x8*)&s0.b0[(c * 2 + 0) * 512 + lane * 8], facc0);
            facc1 = mfma16(a, *(const bf16x8*)&s0.b0[(c * 2 + 1) * 512 + lane * 8], facc1);
        }
    }

    unsigned bc = 0;
    for (int t = 0; t < T_; ++t) {
        const int s_cur = t & 1, s_prev = s_cur ^ 1;

        // ===================== window 1 =====================
        if (isL0) {
            SM0& s0 = smu.a;
            if (t > 0) {
                if (tid < 128) {
                    s0.mu_s[tid] = muacc[(s_prev * 128 + tid) * 32] + s0.mubias;
                    int mi = tid * T_ + t;
                    bool um = !nonbin ? (reinterpret_cast<const int*>(mask)[mi] != 0)
                            : !nonfl  ? (reinterpret_cast<const float*>(mask)[mi] != 0.f)
                                      : (reinterpret_cast<const unsigned char*>(mask)[mi] != 0);
                    s0.msk[tid] = um ? 1 : 0;
                }
                __syncthreads();
                if (tid == 0) {   // WG b-owner writes out[b][t-1]
                    out[((size_t)blk * T_ + (t - 1)) * 2 + 0] = s0.mu_s[blk];
                    out[((size_t)blk * T_ + (t - 1)) * 2 + 1] =
                        softp(sgacc[(s_prev * 128 + blk) * 32] + s0.sgbias);
                }
            }
            // label tile
            for (int i = tid; i < 128 * 64; i += NT) {
                int b = i >> 6, e = i & 63;
                bool um = (t > 0) && s0.msk[b];
                float v = um ? fmaf(s0.mu_s[b], s0.wt[e], s0.bt[e])
                             : emb[((size_t)b * T_ + t) * E_ + e];
                s0.lab[b * 72 + e] = f2bf(v);
            }
            __syncthreads();

            acc0 = facc0; acc1 = facc1;
            #pragma unroll
            for (int c = 0; c < 2; ++c) {      // lab chunks 16,17
                bf16x8 a = *(const bf16x8*)&s0.lab[rowA * 72 + c * 32 + ko];
                acc0 = mfma16(a, *(const bf16x8*)&s0.b0[((16 + c) * 2 + 0) * 512 + lane * 8], acc0);
                acc1 = mfma16(a, *(const bf16x8*)&s0.b0[((16 + c) * 2 + 1) * 512 + lane * 8], acc1);
            }
            if (t > 0) {                        // h0prev chunks 18..49
                const u16* aH = h0b + (size_t)s_prev * BH + (size_t)rowA * H_ + ko;
                #pragma unroll 8
                for (int c = 0; c < 32; ++c) {
                    bf16x8 a = ld8(aH + c * 32);
                    acc0 = mfma16(a, *(const bf16x8*)&s0.b0[((18 + c) * 2 + 0) * 512 + lane * 8], acc0);
                    acc1 = mfma16(a, *(const bf16x8*)&s0.b0[((18 + c) * 2 + 1) * 512 + lane * 8], acc1);
                }
            }
            {
                int rl = w * 16 + quad * 4;
                #pragma unroll
                for (int r = 0; r < 4; ++r) {
                    s0.gt[(rl + r) * 33 + l16]      = acc0[r];
                    s0.gt[(rl + r) * 33 + 16 + l16] = acc1[r];
                }
            }
            __syncthreads();
            // cell0
            u16* h0w = h0b + (size_t)s_cur * BH;
            #pragma unroll
            for (int p = 0; p < 2; ++p) {
                int id = tid + p * NT;
                int b = id >> 3, j = id & 7;
                float gi = s0.gt[b * 33 + 4 * j + 0] + s0.bias0[4 * j + 0];
                float gf = s0.gt[b * 33 + 4 * j + 1] + s0.bias0[4 * j + 1];
                float gg = s0.gt[b * 33 + 4 * j + 2] + s0.bias0[4 * j + 2];
                float go = s0.gt[b * 33 + 4 * j + 3] + s0.bias0[4 * j + 3];
                float cold = (p == 0) ? creg0 : creg1;
                float cn = sigm(gf) * cold + sigm(gi) * tanh_(gg);
                float hn = sigm(go) * tanh_(cn);
                if (p == 0) creg0 = cn; else creg1 = cn;
                h0w[(size_t)b * H_ + g * 8 + j] = f2bf(hn);
                float pmu = hn * s0.mw0[j], psg = hn * s0.sw0[j];
                pmu += __shfl_xor(pmu, 1); pmu += __shfl_xor(pmu, 2); pmu += __shfl_xor(pmu, 4);
                psg += __shfl_xor(psg, 1); psg += __shfl_xor(psg, 2); psg += __shfl_xor(psg, 4);
                if (j == 0) {
                    atomicAdd(&muacc[(s_cur * 128 + b) * 32], pmu);
                    atomicAdd(&sgacc[(s_cur * 128 + b) * 32], psg);
                }
            }
        } else {
            // L1: h1prev GEMM (independent of this step's h0)
            acc0 = f32x4{0, 0, 0, 0}; acc1 = f32x4{0, 0, 0, 0};
            if (t > 0) {
                SM1& s1 = smu.b;
                const u16* aH1 = h1b + (size_t)s_prev * BH + (size_t)rowA * H_ + ko;
                #pragma unroll 8
                for (int c = 0; c < 32; ++c) {
                    bf16x8 a = ld8(aH1 + c * 32);
                    acc0 = mfma16(a, *(const bf16x8*)&s1.b1[((32 + c) * 2 + 0) * 512 + lane * 8], acc0);
                    acc1 = mfma16(a, *(const bf16x8*)&s1.b1[((32 + c) * 2 + 1) * 512 + lane * 8], acc1);
                }
            }
        }
        gbar(ctr, (++bc) * NBLK);   // h0(t) published

        // ===================== window 2 =====================
        if (isL0) {
            if (t + 1 < T_) {       // pre-GEMM feat(t+1)
                SM0& s0 = smu.a;
                facc0 = f32x4{0, 0, 0, 0}; facc1 = f32x4{0, 0, 0, 0};
                const u16* aF = fb + ((size_t)((t + 1) * B_ + rowA)) * FD + ko;
                #pragma unroll
                for (int c = 0; c < 16; ++c) {
                    bf16x8 a = ld8(aF + c * 32);
                    facc0 = mfma16(a, *(const bf16x8*)&s0.b0[(c * 2 + 0) * 512 + lane * 8], facc0);
                    facc1 = mfma16(a, *(const bf16x8*)&s0.b0[(c * 2 + 1) * 512 + lane * 8], facc1);
                }
            }
        } else {
            SM1& s1 = smu.b;
            if (t >= 1 && tid == 0) {   // zero the consumed accumulator slot
                muacc[(s_prev * 128 + g) * 32] = 0.f;
                sgacc[(s_prev * 128 + g) * 32] = 0.f;
            }
            {   // h0(t) chunks 0..31
                const u16* aH0 = h0b + (size_t)s_cur * BH + (size_t)rowA * H_ + ko;
                #pragma unroll 8
                for (int c = 0; c < 32; ++c) {
                    bf16x8 a = ld8(aH0 + c * 32);
                    acc0 = mfma16(a, *(const bf16x8*)&s1.b1[(c * 2 + 0) * 512 + lane * 8], acc0);
                    acc1 = mfma16(a, *(const bf16x8*)&s1.b1[(c * 2 + 1) * 512 + lane * 8], acc1);
                }
            }
            {
                int rl = w * 16 + quad * 4;
                #pragma unroll
                for (int r = 0; r < 4; ++r) {
                    s1.gt[(rl + r) * 33 + l16]      = acc0[r];
                    s1.gt[(rl + r) * 33 + 16 + l16] = acc1[r];
                }
            }
            __syncthreads();
            u16* h1w = h1b + (size_t)s_cur * BH;
            #pragma unroll
            for (int p = 0; p < 2; ++p) {
                int id = tid + p * NT;
                int b = id >> 3, j = id & 7;
                float gi = s1.gt[b * 33 + 4 * j + 0] + s1.bias1[4 * j + 0];
                float gf = s1.gt[b * 33 + 4 * j + 1] + s1.bias1[4 * j + 1];
                float gg = s1.gt[b * 33 + 4 * j + 2] + s1.bias1[4 * j + 2];
                float go = s1.gt[b * 33 + 4 * j + 3] + s1.bias1[4 * j + 3];
                float cold = (p == 0) ? creg0 : creg1;
                float cn = sigm(gf) * cold + sigm(gi) * tanh_(gg);
                float hn = sigm(go) * tanh_(cn);
                if (p == 0) creg0 = cn; else creg1 = cn;
                h1w[(size_t)b * H_ + g * 8 + j] = f2bf(hn);
                float pmu = hn * s1.mw1[j], psg = hn * s1.sw1[j];
                pmu += __shfl_xor(pmu, 1); pmu += __shfl_xor(pmu, 2); pmu += __shfl_xor(pmu, 4);
                psg += __shfl_xor(psg, 1); psg += __shfl_xor(psg, 2); psg += __shfl_xor(psg, 4);
                if (j == 0) {
                    atomicAdd(&muacc[(s_cur * 128 + b) * 32], pmu);
                    atomicAdd(&sgacc[(s_cur * 128 + b) * 32], psg);
                }
            }
        }
        gbar(ctr, (++bc) * NBLK);   // h1(t) + partials published
    }

    // ---- final output t = T_-1 (slot 1) ----
    if (isL0 && tid == 0) {
        float m = muacc[(1 * 128 + blk) * 32] + smu.a.mubias;
        out[((size_t)blk * T_ + (T_ - 1)) * 2 + 0] = m;
        out[((size_t)blk * T_ + (T_ - 1)) * 2 + 1] =
            softp(sgacc[(1 * 128 + blk) * 32] + smu.a.sgbias);
    }
}

// ---------------- host ----------------

extern "C" void kernel_launch(void* const* d_in, const int* in_sizes, int n_in,
                              void* d_out, int out_size, void* d_ws, size_t ws_size,
                              hipStream_t stream) {
    const float* feat = (const float*)d_in[0];
    const float* emb  = (const float*)d_in[1];
    const void*  mask = d_in[2];
    const float* Wih0 = (const float*)d_in[3];
    const float* Whh0 = (const float*)d_in[4];
    const float* bih0 = (const float*)d_in[5];
    const float* bhh0 = (const float*)d_in[6];
    const float* Wih1 = (const float*)d_in[7];
    const float* Whh1 = (const float*)d_in[8];
    const float* bih1 = (const float*)d_in[9];
    const float* bhh1 = (const float*)d_in[10];
    const float* Wtgt = (const float*)d_in[11];
    const float* btgt = (const float*)d_in[12];
    const float* muw  = (const float*)d_in[13];
    const float* mub  = (const float*)d_in[14];
    const float* sgw  = (const float*)d_in[15];
    const float* sgb  = (const float*)d_in[16];
    float* out = (float*)d_out;
    char* ws = (char*)d_ws;
    (void)in_sizes; (void)n_in; (void)out_size; (void)ws_size;

    size_t off = 0;
    auto alloc = [&](size_t bytes) {
        size_t o = off;
        off = (off + bytes + 255) & ~(size_t)255;
        return o;
    };
    size_t o_flags = alloc(256);
    size_t o_ctr   = alloc(256);
    size_t o_muacc = alloc((size_t)2 * 128 * 32 * 4);
    size_t o_sgacc = alloc((size_t)2 * 128 * 32 * 4);
    size_t zero_end = off;
    size_t o_h0    = alloc((size_t)2 * BH * 2);
    size_t o_h1    = alloc((size_t)2 * BH * 2);
    size_t o_fb    = alloc((size_t)T_ * B_ * FD * 2);

    int*      flags = (int*)(ws + o_flags);
    unsigned* ctr   = (unsigned*)(ws + o_ctr);
    float*    muacc = (float*)(ws + o_muacc);
    float*    sgacc = (float*)(ws + o_sgacc);
    u16*      h0    = (u16*)(ws + o_h0);
    u16*      h1    = (u16*)(ws + o_h1);
    u16*      fb    = (u16*)(ws + o_fb);

    hipMemsetAsync(ws, 0, zero_end, stream);
    detect_mask<<<20, 256, 0, stream>>>((const unsigned*)mask, flags);
    featconv<<<10240, 256, 0, stream>>>(feat, fb);

    persist<<<NBLK, NT, 0, stream>>>(
        fb, emb, mask, flags,
        Wih0, Whh0, bih0, bhh0,
        Wih1, Whh1, bih1, bhh1,
        Wtgt, btgt, muw, mub, sgw, sgb,
        h0, h1, muacc, sgacc, ctr, out);
}

// Round 4
// 6124.063 us; speedup vs baseline: 6.9685x; 1.9539x over previous
//
#include <hip/hip_runtime.h>

// DeepAR MI355X round 4: persistent kernel, layer-split WGs, LDS-resident
// weights. Cross-XCD exchange via agent-scope (sc1) stores to LLC; barrier =
// relaxed-poll + single acquire-inv per WG (no wbl2, no inv storm).
// B=128, T=160, F=512, E=64, H=1024, L=2. Output [B,T,2] fp32.
//
// WGs 0..127   : layer 0, gate cols for hidden g*8..g*8+7, all M=128 rows.
// WGs 128..255 : layer 1, same col ownership.
// Step t (2 barriers):
//  W1: L0: issue mu(t-1)/mask loads -> h0prev GEMM (feat acc carried) ->
//      lab build+GEMM -> cell0 -> publish h0(t) [agent stores] + partial
//      atomics. L1: h1prev GEMM.                      == barrier ==
//  W2: L0: pre-GEMM feat(t+1). L1: zero consumed muacc slot, h0(t) GEMM,
//      cell1, publish h1(t) + partial atomics.        == barrier ==

#define B_   128
#define T_   160
#define FD   512
#define E_   64
#define H_   1024
#define NT   512
#define NBLK 256
#define BH   (B_ * H_)

typedef unsigned short u16;
typedef __attribute__((ext_vector_type(8))) short bf16x8;
typedef __attribute__((ext_vector_type(4))) float f32x4;

__device__ __forceinline__ bf16x8 ld8(const u16* p) {
    return *reinterpret_cast<const bf16x8*>(p);
}
__device__ __forceinline__ f32x4 mfma16(bf16x8 a, bf16x8 b, f32x4 c) {
    return __builtin_amdgcn_mfma_f32_16x16x32_bf16(a, b, c, 0, 0, 0);
}
__device__ __forceinline__ u16 f2bf(float x) {
    unsigned u = __float_as_uint(x);
    u += 0x7FFFu + ((u >> 16) & 1u);   // RNE
    return (u16)(u >> 16);
}
__device__ __forceinline__ float sigm(float x)  { return 1.f / (1.f + __expf(-x)); }
__device__ __forceinline__ float tanh_(float x) { return 1.f - 2.f / (__expf(2.f * x) + 1.f); }
__device__ __forceinline__ float softp(float x) { return x > 20.f ? x : log1pf(__expf(x)); }

// agent-scope (LLC-direct, sc1) helpers — never dirty the local L2
__device__ __forceinline__ void st_u32(unsigned* p, unsigned v) {
    __hip_atomic_store(p, v, __ATOMIC_RELAXED, __HIP_MEMORY_SCOPE_AGENT);
}
__device__ __forceinline__ void st_f32(float* p, float v) {
    __hip_atomic_store(p, v, __ATOMIC_RELAXED, __HIP_MEMORY_SCOPE_AGENT);
}

// Grid barrier: 8 spread arrival lines; WG0 aggregates -> release flag.
// Pollers use RELAXED loads (no inv); ONE acquire load (one buffer_inv) per
// WG per barrier, after release.
__device__ __forceinline__ void gbar(unsigned* actr, unsigned* rel, int blk, unsigned phase) {
    __syncthreads();   // drains vmcnt: all agent stores/atomics at LLC
    if (threadIdx.x == 0) {
        __hip_atomic_fetch_add(&actr[(blk & 7) * 32], 1u,
                               __ATOMIC_RELAXED, __HIP_MEMORY_SCOPE_AGENT);
        if (blk == 0) {
            for (;;) {
                unsigned s = 0;
                #pragma unroll
                for (int i = 0; i < 8; ++i)
                    s += __hip_atomic_load(&actr[i * 32], __ATOMIC_RELAXED,
                                           __HIP_MEMORY_SCOPE_AGENT);
                if (s >= (unsigned)NBLK * phase) break;
                __builtin_amdgcn_s_sleep(2);
            }
            __hip_atomic_store(rel, phase, __ATOMIC_RELAXED, __HIP_MEMORY_SCOPE_AGENT);
        } else {
            while (__hip_atomic_load(rel, __ATOMIC_RELAXED, __HIP_MEMORY_SCOPE_AGENT) < phase)
                __builtin_amdgcn_s_sleep(2);
        }
        (void)__hip_atomic_load(rel, __ATOMIC_ACQUIRE, __HIP_MEMORY_SCOPE_AGENT); // 1 inv
    }
    __syncthreads();
}

// ---------------- prologue kernels ----------------

__global__ void detect_mask(const unsigned* __restrict__ m, int* __restrict__ flags) {
    int i = blockIdx.x * 256 + threadIdx.x;   // first 5120 words, safe in all interps
    unsigned w = m[i];
    if (w > 1u) atomicOr(&flags[0], 1);
    if (w != 0u && w != 0x3F800000u) atomicOr(&flags[1], 1);
}

// feat [B][T][512] fp32 -> fb [T][B][512] bf16
__global__ void featconv(const float* __restrict__ feat, u16* __restrict__ fb) {
    int i = blockIdx.x * 256 + threadIdx.x;   // [0, 160*128*128) float4 units
    int kv = i & 127;
    int b  = (i >> 7) & 127;
    int t  = i >> 14;
    float4 v = reinterpret_cast<const float4*>(feat)[((size_t)(b * T_ + t)) * 128 + kv];
    ushort4 o = make_ushort4(f2bf(v.x), f2bf(v.y), f2bf(v.z), f2bf(v.w));
    reinterpret_cast<ushort4*>(fb)[((size_t)(t * B_ + b)) * 128 + kv] = o;
}

// ---------------- persistent kernel ----------------

struct SM0 {                       // layer-0 WGs
    u16   b0[50 * 1024];           // frag-linear: ((c*2+f)*64 + lane)*8 + jj
    u16   lab[128 * 72];           // label tile
    float gt[128 * 33];
    float mu_s[128];
    unsigned char msk[128];
    float wt[64], bt[64];
    float bias0[32];
    float mw0[8], sw0[8];
};
struct SM1 {                       // layer-1 WGs
    u16   b1[64 * 1024];
    float gt[128 * 33];
    float bias1[32];
    float mw1[8], sw1[8];
};
union SMU { SM0 a; SM1 b; };

__global__ void __launch_bounds__(NT, 2) persist(
    const u16* __restrict__ fb, const float* __restrict__ emb,
    const void* __restrict__ mask, const int* __restrict__ flags,
    const float* __restrict__ Wih0, const float* __restrict__ Whh0,
    const float* __restrict__ bih0, const float* __restrict__ bhh0,
    const float* __restrict__ Wih1, const float* __restrict__ Whh1,
    const float* __restrict__ bih1, const float* __restrict__ bhh1,
    const float* __restrict__ Wtgt, const float* __restrict__ btgt,
    const float* __restrict__ muw, const float* __restrict__ mubp,
    const float* __restrict__ sgw, const float* __restrict__ sgbp,
    u16* __restrict__ h0b, u16* __restrict__ h1b,
    float* __restrict__ muacc, float* __restrict__ sgacc,
    unsigned* __restrict__ actr, unsigned* __restrict__ rel,
    float* __restrict__ out)
{
    __shared__ SMU smu;
    const int tid  = threadIdx.x;
    const int blk  = blockIdx.x;
    const bool isL0 = blk < 128;
    const int g    = isL0 ? blk : blk - 128;   // hidden units g*8..g*8+7
    const int w    = tid >> 6;
    const int lane = tid & 63;
    const int quad = lane >> 4;
    const int l16  = lane & 15;
    const int ko   = quad * 8;
    const int rowA = w * 16 + l16;

    const float mub_r = mubp[0];
    const float sgb_r = sgbp[0];

    // ---- one-time init: pack this WG's weight slice into LDS ----
    if (isL0) {
        SM0& s0 = smu.a;
        for (int i = tid; i < 32 * 1600; i += NT) {
            int col = i / 1600;
            int k   = i - col * 1600;
            int q = col & 3, j = col >> 2;
            int row = q * H_ + g * 8 + j;
            float v = (k < 576) ? Wih0[row * 576 + k]
                                : Whh0[(size_t)row * H_ + (k - 576)];
            int c = k >> 5, q8 = (k >> 3) & 3, jj = k & 7;
            int f = col >> 4, l = col & 15;
            s0.b0[((c * 2 + f) * 64 + q8 * 16 + l) * 8 + jj] = f2bf(v);
        }
        if (tid < 64) { s0.wt[tid] = Wtgt[tid]; s0.bt[tid] = btgt[tid]; }
        if (tid < 32) {
            int q = tid & 3, j = tid >> 2, row = q * H_ + g * 8 + j;
            s0.bias0[tid] = bih0[row] + bhh0[row];
        }
        if (tid < 8) {
            int h = g * 8 + tid;
            s0.mw0[tid] = muw[2 * h]; s0.sw0[tid] = sgw[2 * h];
        }
    } else {
        SM1& s1 = smu.b;
        for (int i = tid; i < 32 * 2048; i += NT) {
            int col = i >> 11, k = i & 2047;
            int q = col & 3, j = col >> 2;
            int row = q * H_ + g * 8 + j;
            float v = (k < 1024) ? Wih1[(size_t)row * H_ + k]
                                 : Whh1[(size_t)row * H_ + (k - 1024)];
            int c = k >> 5, q8 = (k >> 3) & 3, jj = k & 7;
            int f = col >> 4, l = col & 15;
            s1.b1[((c * 2 + f) * 64 + q8 * 16 + l) * 8 + jj] = f2bf(v);
        }
        if (tid < 32) {
            int q = tid & 3, j = tid >> 2, row = q * H_ + g * 8 + j;
            s1.bias1[tid] = bih1[row] + bhh1[row];
        }
        if (tid < 8) {
            int h = g * 8 + tid;
            s1.mw1[tid] = muw[2 * h + 1]; s1.sw1[tid] = sgw[2 * h + 1];
        }
    }
    const int nonbin = flags[0], nonfl = flags[1];
    __syncthreads();

    float creg0 = 0.f, creg1 = 0.f;            // per-thread cell state
    f32x4 facc0 = {0,0,0,0}, facc1 = {0,0,0,0};
    f32x4 acc0, acc1;

    // feat GEMM for t=0 (L0 only)
    if (isL0) {
        SM0& s0 = smu.a;
        const u16* aF = fb + ((size_t)rowA) * FD + ko;
        #pragma unroll
        for (int c = 0; c < 16; ++c) {
            bf16x8 a = ld8(aF + c * 32);
            facc0 = mfma16(a, *(const bf16x8*)&s0.b0[(c * 2 + 0) * 512 + lane * 8], facc0);
            facc1 = mfma16(a, *(const bf16x8*)&s0.b0[(c * 2 + 1) * 512 + lane * 8], facc1);
        }
    }

    unsigned bc = 0;
    for (int t = 0; t < T_; ++t) {
        const int s_cur = t & 1, s_prev = s_cur ^ 1;

        // ===================== window 1 =====================
        if (isL0) {
            SM0& s0 = smu.a;
            float sg_own = 0.f;
            if (t > 0) {
                // issue LLC-latency loads early; consumed after the GEMM
                if (tid < 128) {
                    s0.mu_s[tid] = muacc[(s_prev * 128 + tid) * 32] + mub_r;
                    int mi = tid * T_ + t;
                    bool um = !nonbin ? (reinterpret_cast<const int*>(mask)[mi] != 0)
                            : !nonfl  ? (reinterpret_cast<const float*>(mask)[mi] != 0.f)
                                      : (reinterpret_cast<const unsigned char*>(mask)[mi] != 0);
                    s0.msk[tid] = um ? 1 : 0;
                }
                if (tid == 0) sg_own = sgacc[(s_prev * 128 + blk) * 32] + sgb_r;
            }

            acc0 = facc0; acc1 = facc1;
            if (t > 0) {                        // h0prev chunks 18..49
                const u16* aH = h0b + (size_t)s_prev * BH + (size_t)rowA * H_ + ko;
                #pragma unroll 8
                for (int c = 0; c < 32; ++c) {
                    bf16x8 a = ld8(aH + c * 32);
                    acc0 = mfma16(a, *(const bf16x8*)&s0.b0[((18 + c) * 2 + 0) * 512 + lane * 8], acc0);
                    acc1 = mfma16(a, *(const bf16x8*)&s0.b0[((18 + c) * 2 + 1) * 512 + lane * 8], acc1);
                }
            }
            __syncthreads();                    // mu_s/msk visible
            if (t > 0 && tid == 0) {            // out[b=blk][t-1]
                st_f32(&out[((size_t)blk * T_ + (t - 1)) * 2 + 0], s0.mu_s[blk]);
                st_f32(&out[((size_t)blk * T_ + (t - 1)) * 2 + 1], softp(sg_own));
            }
            // label tile
            for (int i = tid; i < 128 * 64; i += NT) {
                int b = i >> 6, e = i & 63;
                bool um = (t > 0) && s0.msk[b];
                float v = um ? fmaf(s0.mu_s[b], s0.wt[e], s0.bt[e])
                             : emb[((size_t)b * T_ + t) * E_ + e];
                s0.lab[b * 72 + e] = f2bf(v);
            }
            __syncthreads();
            #pragma unroll
            for (int c = 0; c < 2; ++c) {       // lab chunks 16,17
                bf16x8 a = *(const bf16x8*)&s0.lab[rowA * 72 + c * 32 + ko];
                acc0 = mfma16(a, *(const bf16x8*)&s0.b0[((16 + c) * 2 + 0) * 512 + lane * 8], acc0);
                acc1 = mfma16(a, *(const bf16x8*)&s0.b0[((16 + c) * 2 + 1) * 512 + lane * 8], acc1);
            }
            {
                int rl = w * 16 + quad * 4;
                #pragma unroll
                for (int r = 0; r < 4; ++r) {
                    s0.gt[(rl + r) * 33 + l16]      = acc0[r];
                    s0.gt[(rl + r) * 33 + 16 + l16] = acc1[r];
                }
            }
            __syncthreads();
            // cell0: task (b = id>>3, j = id&7)
            u16* h0w = h0b + (size_t)s_cur * BH;
            #pragma unroll
            for (int p = 0; p < 2; ++p) {
                int id = tid + p * NT;
                int b = id >> 3, j = id & 7;
                float gi = s0.gt[b * 33 + 4 * j + 0] + s0.bias0[4 * j + 0];
                float gf = s0.gt[b * 33 + 4 * j + 1] + s0.bias0[4 * j + 1];
                float gg = s0.gt[b * 33 + 4 * j + 2] + s0.bias0[4 * j + 2];
                float go = s0.gt[b * 33 + 4 * j + 3] + s0.bias0[4 * j + 3];
                float cold = (p == 0) ? creg0 : creg1;
                float cn = sigm(gf) * cold + sigm(gi) * tanh_(gg);
                float hn = sigm(go) * tanh_(cn);
                if (p == 0) creg0 = cn; else creg1 = cn;
                unsigned hv = f2bf(hn);
                unsigned other = (unsigned)__shfl_xor((int)hv, 1);
                if ((j & 1) == 0)   // packed u32 agent store (LLC-direct)
                    st_u32(reinterpret_cast<unsigned*>(h0w + (size_t)b * H_ + g * 8 + j),
                           hv | (other << 16));
                float pmu = hn * s0.mw0[j], psg = hn * s0.sw0[j];
                pmu += __shfl_xor(pmu, 1); pmu += __shfl_xor(pmu, 2); pmu += __shfl_xor(pmu, 4);
                psg += __shfl_xor(psg, 1); psg += __shfl_xor(psg, 2); psg += __shfl_xor(psg, 4);
                if (j == 0) {
                    atomicAdd(&muacc[(s_cur * 128 + b) * 32], pmu);
                    atomicAdd(&sgacc[(s_cur * 128 + b) * 32], psg);
                }
            }
        } else {
            // L1: h1prev GEMM (independent of this step's h0)
            acc0 = f32x4{0, 0, 0, 0}; acc1 = f32x4{0, 0, 0, 0};
            if (t > 0) {
                SM1& s1 = smu.b;
                const u16* aH1 = h1b + (size_t)s_prev * BH + (size_t)rowA * H_ + ko;
                #pragma unroll 8
                for (int c = 0; c < 32; ++c) {
                    bf16x8 a = ld8(aH1 + c * 32);
                    acc0 = mfma16(a, *(const bf16x8*)&s1.b1[((32 + c) * 2 + 0) * 512 + lane * 8], acc0);
                    acc1 = mfma16(a, *(const bf16x8*)&s1.b1[((32 + c) * 2 + 1) * 512 + lane * 8], acc1);
                }
            }
        }
        gbar(actr, rel, blk, ++bc);   // h0(t) + L0 partials at LLC

        // ===================== window 2 =====================
        if (isL0) {
            if (t + 1 < T_) {       // pre-GEMM feat(t+1)
                SM0& s0 = smu.a;
                facc0 = f32x4{0, 0, 0, 0}; facc1 = f32x4{0, 0, 0, 0};
                const u16* aF = fb + ((size_t)((t + 1) * B_ + rowA)) * FD + ko;
                #pragma unroll
                for (int c = 0; c < 16; ++c) {
                    bf16x8 a = ld8(aF + c * 32);
                    facc0 = mfma16(a, *(const bf16x8*)&s0.b0[(c * 2 + 0) * 512 + lane * 8], facc0);
                    facc1 = mfma16(a, *(const bf16x8*)&s0.b0[(c * 2 + 1) * 512 + lane * 8], facc1);
                }
            }
        } else {
            SM1& s1 = smu.b;
            if (tid == 0) {          // zero the consumed accumulator slot (LLC-direct)
                st_f32(&muacc[(s_prev * 128 + g) * 32], 0.f);
                st_f32(&sgacc[(s_prev * 128 + g) * 32], 0.f);
            }
            {   // h0(t) chunks 0..31
                const u16* aH0 = h0b + (size_t)s_cur * BH + (size_t)rowA * H_ + ko;
                #pragma unroll 8
                for (int c = 0; c < 32; ++c) {
                    bf16x8 a = ld8(aH0 + c * 32);
                    acc0 = mfma16(a, *(const bf16x8*)&s1.b1[(c * 2 + 0) * 512 + lane * 8], acc0);
                    acc1 = mfma16(a, *(const bf16x8*)&s1.b1[(c * 2 + 1) * 512 + lane * 8], acc1);
                }
            }
            {
                int rl = w * 16 + quad * 4;
                #pragma unroll
                for (int r = 0; r < 4; ++r) {
                    s1.gt[(rl + r) * 33 + l16]      = acc0[r];
                    s1.gt[(rl + r) * 33 + 16 + l16] = acc1[r];
                }
            }
            __syncthreads();
            u16* h1w = h1b + (size_t)s_cur * BH;
            #pragma unroll
            for (int p = 0; p < 2; ++p) {
                int id = tid + p * NT;
                int b = id >> 3, j = id & 7;
                float gi = s1.gt[b * 33 + 4 * j + 0] + s1.bias1[4 * j + 0];
                float gf = s1.gt[b * 33 + 4 * j + 1] + s1.bias1[4 * j + 1];
                float gg = s1.gt[b * 33 + 4 * j + 2] + s1.bias1[4 * j + 2];
                float go = s1.gt[b * 33 + 4 * j + 3] + s1.bias1[4 * j + 3];
                float cold = (p == 0) ? creg0 : creg1;
                float cn = sigm(gf) * cold + sigm(gi) * tanh_(gg);
                float hn = sigm(go) * tanh_(cn);
                if (p == 0) creg0 = cn; else creg1 = cn;
                unsigned hv = f2bf(hn);
                unsigned other = (unsigned)__shfl_xor((int)hv, 1);
                if ((j & 1) == 0)
                    st_u32(reinterpret_cast<unsigned*>(h1w + (size_t)b * H_ + g * 8 + j),
                           hv | (other << 16));
                float pmu = hn * s1.mw1[j], psg = hn * s1.sw1[j];
                pmu += __shfl_xor(pmu, 1); pmu += __shfl_xor(pmu, 2); pmu += __shfl_xor(pmu, 4);
                psg += __shfl_xor(psg, 1); psg += __shfl_xor(psg, 2); psg += __shfl_xor(psg, 4);
                if (j == 0) {
                    atomicAdd(&muacc[(s_cur * 128 + b) * 32], pmu);
                    atomicAdd(&sgacc[(s_cur * 128 + b) * 32], psg);
                }
            }
        }
        gbar(actr, rel, blk, ++bc);   // h1(t) + all partials at LLC
    }

    // ---- final output t = T_-1 (slot 1) ----
    if (isL0 && tid == 0) {
        float m = muacc[(1 * 128 + blk) * 32] + mub_r;
        st_f32(&out[((size_t)blk * T_ + (T_ - 1)) * 2 + 0], m);
        st_f32(&out[((size_t)blk * T_ + (T_ - 1)) * 2 + 1],
               softp(sgacc[(1 * 128 + blk) * 32] + sgb_r));
    }
}

// ---------------- host ----------------

extern "C" void kernel_launch(void* const* d_in, const int* in_sizes, int n_in,
                              void* d_out, int out_size, void* d_ws, size_t ws_size,
                              hipStream_t stream) {
    const float* feat = (const float*)d_in[0];
    const float* emb  = (const float*)d_in[1];
    const void*  mask = d_in[2];
    const float* Wih0 = (const float*)d_in[3];
    const float* Whh0 = (const float*)d_in[4];
    const float* bih0 = (const float*)d_in[5];
    const float* bhh0 = (const float*)d_in[6];
    const float* Wih1 = (const float*)d_in[7];
    const float* Whh1 = (const float*)d_in[8];
    const float* bih1 = (const float*)d_in[9];
    const float* bhh1 = (const float*)d_in[10];
    const float* Wtgt = (const float*)d_in[11];
    const float* btgt = (const float*)d_in[12];
    const float* muw  = (const float*)d_in[13];
    const float* mub  = (const float*)d_in[14];
    const float* sgw  = (const float*)d_in[15];
    const float* sgb  = (const float*)d_in[16];
    float* out = (float*)d_out;
    char* ws = (char*)d_ws;
    (void)in_sizes; (void)n_in; (void)out_size; (void)ws_size;

    size_t off = 0;
    auto alloc = [&](size_t bytes) {
        size_t o = off;
        off = (off + bytes + 255) & ~(size_t)255;
        return o;
    };
    size_t o_flags = alloc(256);
    size_t o_actr  = alloc(8 * 32 * 4);
    size_t o_rel   = alloc(256);
    size_t o_muacc = alloc((size_t)2 * 128 * 32 * 4);
    size_t o_sgacc = alloc((size_t)2 * 128 * 32 * 4);
    size_t zero_end = off;
    size_t o_h0    = alloc((size_t)2 * BH * 2);
    size_t o_h1    = alloc((size_t)2 * BH * 2);
    size_t o_fb    = alloc((size_t)T_ * B_ * FD * 2);

    int*      flags = (int*)(ws + o_flags);
    unsigned* actr  = (unsigned*)(ws + o_actr);
    unsigned* rel   = (unsigned*)(ws + o_rel);
    float*    muacc = (float*)(ws + o_muacc);
    float*    sgacc = (float*)(ws + o_sgacc);
    u16*      h0    = (u16*)(ws + o_h0);
    u16*      h1    = (u16*)(ws + o_h1);
    u16*      fb    = (u16*)(ws + o_fb);

    hipMemsetAsync(ws, 0, zero_end, stream);
    detect_mask<<<20, 256, 0, stream>>>((const unsigned*)mask, flags);
    featconv<<<10240, 256, 0, stream>>>(feat, fb);

    persist<<<NBLK, NT, 0, stream>>>(
        fb, emb, mask, flags,
        Wih0, Whh0, bih0, bhh0,
        Wih1, Whh1, bih1, bhh1,
        Wtgt, btgt, muw, mub, sgw, sgb,
        h0, h1, muacc, sgacc, actr, rel, out);
}

// Round 5
// 4650.051 us; speedup vs baseline: 9.1774x; 1.3170x over previous
//
#include <hip/hip_runtime.h>

// DeepAR MI355X round 5: persistent kernel, layer-split WGs, LDS weights in
// 32x32x16-MFMA fragment layout, 8 waves = 4 M-tiles x 2-way K-split,
// h-state exchanged in MFMA-fragment tiles (full-line coalesced stores, no
// sub-line RMW), rank-1 mu-label trick moves all mu-dependent GEMM work out
// of the critical window. Barrier: round-4 scheme (relaxed poll + one
// acquire-inv per WG per barrier).
// B=128, T=160, F=512, E=64, H=1024, L=2. Output [B,T,2] fp32.

#define B_   128
#define T_   160
#define FD   512
#define E_   64
#define H_   1024
#define NT   512
#define NBLK 256
#define CH0  100                     // L0 K-chunks (K=1600: 32 feat, 4 lab, 64 h0)
#define CH1  128                     // L1 K-chunks (K=2048: 64 h0cur, 64 h1prev)
#define HT_ELEMS (64 * 4 * 512)      // per-parity h tile elems (= B_*H_)

typedef unsigned short u16;
typedef __attribute__((ext_vector_type(8))) short bf16x8;
typedef __attribute__((ext_vector_type(16))) float f32x16;

__device__ __forceinline__ bf16x8 ld8(const u16* p) {
    return *reinterpret_cast<const bf16x8*>(p);
}
__device__ __forceinline__ f32x16 mfma32(bf16x8 a, bf16x8 b, f32x16 c) {
    return __builtin_amdgcn_mfma_f32_32x32x16_bf16(a, b, c, 0, 0, 0);
}
__device__ __forceinline__ u16 f2bf(float x) {
    unsigned u = __float_as_uint(x);
    u += 0x7FFFu + ((u >> 16) & 1u);   // RNE
    return (u16)(u >> 16);
}
__device__ __forceinline__ float sigm(float x)  { return 1.f / (1.f + __expf(-x)); }
__device__ __forceinline__ float tanh_(float x) { return 1.f - 2.f / (__expf(2.f * x) + 1.f); }
__device__ __forceinline__ float softp(float x) { return x > 20.f ? x : log1pf(__expf(x)); }

__device__ __forceinline__ void st_u32(unsigned* p, unsigned v) {
    __hip_atomic_store(p, v, __ATOMIC_RELAXED, __HIP_MEMORY_SCOPE_AGENT);
}
__device__ __forceinline__ void st_f32(float* p, float v) {
    __hip_atomic_store(p, v, __ATOMIC_RELAXED, __HIP_MEMORY_SCOPE_AGENT);
}

// Grid barrier (round-4 proven): 8 spread arrival lines; WG0 aggregates ->
// release flag. Relaxed polls (no inv); ONE acquire (one inv) per WG.
__device__ __forceinline__ void gbar(unsigned* actr, unsigned* rel, int blk, unsigned phase) {
    __syncthreads();   // drains vmcnt: all agent stores/atomics at LLC
    if (threadIdx.x == 0) {
        __hip_atomic_fetch_add(&actr[(blk & 7) * 32], 1u,
                               __ATOMIC_RELAXED, __HIP_MEMORY_SCOPE_AGENT);
        if (blk == 0) {
            for (;;) {
                unsigned s = 0;
                #pragma unroll
                for (int i = 0; i < 8; ++i)
                    s += __hip_atomic_load(&actr[i * 32], __ATOMIC_RELAXED,
                                           __HIP_MEMORY_SCOPE_AGENT);
                if (s >= (unsigned)NBLK * phase) break;
                __builtin_amdgcn_s_sleep(2);
            }
            __hip_atomic_store(rel, phase, __ATOMIC_RELAXED, __HIP_MEMORY_SCOPE_AGENT);
        } else {
            while (__hip_atomic_load(rel, __ATOMIC_RELAXED, __HIP_MEMORY_SCOPE_AGENT) < phase)
                __builtin_amdgcn_s_sleep(2);
        }
        (void)__hip_atomic_load(rel, __ATOMIC_ACQUIRE, __HIP_MEMORY_SCOPE_AGENT); // 1 inv
    }
    __syncthreads();
}

// ---------------- prologue kernels ----------------

__global__ void detect_mask(const unsigned* __restrict__ m, int* __restrict__ flags) {
    int i = blockIdx.x * 256 + threadIdx.x;   // exactly 5120 words (20480 bytes)
    unsigned w = m[i];
    if (w > 1u) atomicOr(&flags[0], 1);
    if (w != 0u && w != 0x3F800000u) atomicOr(&flags[1], 1);
}

// feat [B][T][512] fp32 -> fb2 [T][c=32][mblk=4][512] bf16 (MFMA A-frag tiles)
__global__ void featconv(const float* __restrict__ feat, u16* __restrict__ fb2) {
    int i = blockIdx.x * 256 + threadIdx.x;   // [0, 160*16384) float4 units
    int t = i >> 14;
    int u = i & 16383;
    int c = u >> 9;
    int r = u & 511;
    int mm = r >> 7;
    int l  = (r >> 1) & 63;
    int jj = r & 1;
    int b = mm * 32 + (l & 31);
    int k = c * 16 + (l >> 5) * 8 + jj * 4;
    float4 v = reinterpret_cast<const float4*>(feat)[((size_t)b * T_ + t) * 128 + (k >> 2)];
    ushort4 o = make_ushort4(f2bf(v.x), f2bf(v.y), f2bf(v.z), f2bf(v.w));
    reinterpret_cast<ushort4*>(fb2)[((((size_t)t * 32 + c) * 4 + mm) * 512 + l * 8 + jj * 4) >> 2] = o;
}

// ---------------- persistent kernel ----------------

struct SM0 {                       // layer-0 WGs
    u16   bw[CH0 * 512];           // 102400 B, B-frags: bw[ch*512 + lane*8 + j]
    u16   labf[4 * 4 * 512];       // 16384 B, label A-frag tiles
    float gtb[4224];               // 16896 B: K-reduce scratch [16][256] / gates [128][33]
    float mu_s[128];
    float uu[32], vv[32], bias[32];
    float mwv[8], swv[8];
    unsigned char msk[128];
};
struct SM1 {                       // layer-1 WGs
    u16   bw[CH1 * 512];           // 131072 B
    float gtb[4224];
    float bias[32];
    float mwv[8], swv[8];
};
union SMU { SM0 a; SM1 b; };

__global__ void __launch_bounds__(NT, 2) persist(
    const u16* __restrict__ fb2, const float* __restrict__ emb,
    const void* __restrict__ mask, const int* __restrict__ flags,
    const float* __restrict__ Wih0, const float* __restrict__ Whh0,
    const float* __restrict__ bih0, const float* __restrict__ bhh0,
    const float* __restrict__ Wih1, const float* __restrict__ Whh1,
    const float* __restrict__ bih1, const float* __restrict__ bhh1,
    const float* __restrict__ Wtgt, const float* __restrict__ btgt,
    const float* __restrict__ muw, const float* __restrict__ mubp,
    const float* __restrict__ sgw, const float* __restrict__ sgbp,
    u16* __restrict__ h0T, u16* __restrict__ h1T,
    float* __restrict__ muacc, float* __restrict__ sgacc,
    unsigned* __restrict__ actr, unsigned* __restrict__ relf,
    float* __restrict__ out)
{
    __shared__ SMU smu;
    const int tid  = threadIdx.x;
    const int blk  = blockIdx.x;
    const bool isL0 = blk < 128;
    const int g    = isL0 ? blk : blk - 128;   // hidden units g*8..g*8+7
    const int wv   = tid >> 6;
    const int m    = wv & 3;                   // M-tile (rows m*32..m*32+31)
    const int s    = wv >> 2;                  // K-split half
    const int lane = tid & 63;
    const int l31  = lane & 31;

    const float mub_r = mubp[0], sgb_r = sgbp[0];

    // ---- one-time init: pack weights into MFMA B-frag layout in LDS ----
    if (isL0) {
        SM0& s0 = smu.a;
        for (int i = tid; i < CH0 * 512; i += NT) {
            int ch = i >> 9, r = i & 511, l = r >> 3, jj = r & 7;
            int pc = l & 31;
            int kk = ch * 16 + (l >> 5) * 8 + jj;
            int q = pc & 3, j = pc >> 2;
            int row = q * H_ + g * 8 + j;
            float v = (kk < 576) ? Wih0[row * 576 + kk]
                                 : Whh0[(size_t)row * H_ + (kk - 576)];
            s0.bw[i] = f2bf(v);
        }
        if (tid < 32) {
            int pc = tid, q = pc & 3, j = pc >> 2;
            int row = q * H_ + g * 8 + j;
            s0.bias[pc] = bih0[row] + bhh0[row];
            float su = 0.f, sv = 0.f;
            for (int e = 0; e < 64; ++e) {       // rank-1 label vectors
                float wl = Wih0[row * 576 + 512 + e];
                su += Wtgt[e] * wl;
                sv += btgt[e] * wl;
            }
            s0.uu[pc] = su; s0.vv[pc] = sv;
        }
        if (tid < 8) {
            int h = g * 8 + tid;
            s0.mwv[tid] = muw[2 * h]; s0.swv[tid] = sgw[2 * h];
        }
    } else {
        SM1& s1 = smu.b;
        for (int i = tid; i < CH1 * 512; i += NT) {
            int ch = i >> 9, r = i & 511, l = r >> 3, jj = r & 7;
            int pc = l & 31;
            int kk = ch * 16 + (l >> 5) * 8 + jj;
            int q = pc & 3, j = pc >> 2;
            int row = q * H_ + g * 8 + j;
            float v = (kk < 1024) ? Wih1[(size_t)row * H_ + kk]
                                  : Whh1[(size_t)row * H_ + (kk - 1024)];
            s1.bw[i] = f2bf(v);
        }
        if (tid < 32) {
            int pc = tid, q = pc & 3, j = pc >> 2;
            int row = q * H_ + g * 8 + j;
            s1.bias[pc] = bih1[row] + bhh1[row];
        }
        if (tid < 8) {
            int h = g * 8 + tid;
            s1.mwv[tid] = muw[2 * h + 1]; s1.swv[tid] = sgw[2 * h + 1];
        }
    }
    const int nonbin = flags[0], nonfl = flags[1];
    __syncthreads();

    float creg0 = 0.f, creg1 = 0.f;
    f32x16 acc;
    #pragma unroll
    for (int r = 0; r < 16; ++r) acc[r] = 0.f;

    // label tile builder (A-frag layout; mask-zeroed rows when use_mask)
    auto build_lab = [&](int t1, bool use_mask) {
        SM0& s0 = smu.a;
        for (int i = tid; i < 8192; i += NT) {
            int e = i & 63, b = i >> 6;
            bool um = false;
            if (use_mask) {
                int mi = b * T_ + t1;
                um = !nonbin ? (reinterpret_cast<const int*>(mask)[mi] != 0)
                   : !nonfl  ? (reinterpret_cast<const float*>(mask)[mi] != 0.f)
                             : (reinterpret_cast<const unsigned char*>(mask)[mi] != 0);
            }
            float v = um ? 0.f : emb[((size_t)b * T_ + t1) * E_ + e];
            int c = e >> 4, kk = e & 15, hk = kk >> 3, j = kk & 7;
            int l = hk * 32 + (b & 31), mb = b >> 5;
            s0.labf[(c * 4 + mb) * 512 + l * 8 + j] = f2bf(v);
        }
    };

    // pre-loop: feat(0)+lab(0) GEMM (window-2 equivalent for t=-1)
    if (isL0) {
        build_lab(0, false);
        __syncthreads();
        SM0& s0 = smu.a;
        #pragma unroll 6
        for (int c = 0; c < 18; ++c) {
            int ch = s * 18 + c;
            bf16x8 a;
            if (ch < 32) a = ld8(fb2 + (((size_t)0 * 32 + ch) * 4 + m) * 512 + lane * 8);
            else         a = *(const bf16x8*)&s0.labf[((ch - 32) * 4 + m) * 512 + lane * 8];
            bf16x8 b = *(const bf16x8*)&s0.bw[ch * 512 + lane * 8];
            acc = mfma32(a, b, acc);
        }
    }

    unsigned bc = 0;
    for (int t = 0; t < T_; ++t) {
        const int pcur = t & 1, pprev = pcur ^ 1;

        // ===================== window 1 =====================
        if (isL0) {
            SM0& s0 = smu.a;
            if (t > 0) {
                if (tid < 128) {     // mu(t-1) + mask(t), latency hidden by GEMM
                    const float4* pa = (const float4*)&muacc[(pprev * 128 + tid) * 8];
                    float4 x = pa[0], y = pa[1];
                    s0.mu_s[tid] = (x.x + x.y) + (x.z + x.w) + (y.x + y.y) + (y.z + y.w) + mub_r;
                    int mi = tid * T_ + t;
                    bool um = !nonbin ? (reinterpret_cast<const int*>(mask)[mi] != 0)
                            : !nonfl  ? (reinterpret_cast<const float*>(mask)[mi] != 0.f)
                                      : (reinterpret_cast<const unsigned char*>(mask)[mi] != 0);
                    s0.msk[tid] = um ? 1 : 0;
                }
                const u16* hp = h0T + (size_t)pprev * HT_ELEMS;
                #pragma unroll 8
                for (int c = 0; c < 32; ++c) {
                    int ch = s * 32 + c;
                    bf16x8 a = ld8(hp + ((size_t)ch * 4 + m) * 512 + lane * 8);
                    bf16x8 b = *(const bf16x8*)&s0.bw[(36 + ch) * 512 + lane * 8];
                    acc = mfma32(a, b, acc);
                }
            }
            // K-split reduce -> gates
            if (s == 1) {
                #pragma unroll
                for (int r = 0; r < 16; ++r) s0.gtb[r * 256 + m * 64 + lane] = acc[r];
            }
            __syncthreads();
            if (t > 0 && tid == 0) {
                const float4* ps = (const float4*)&sgacc[(pprev * 128 + g) * 8];
                float4 x = ps[0], y = ps[1];
                float sg = (x.x + x.y) + (x.z + x.w) + (y.x + y.y) + (y.z + y.w) + sgb_r;
                out[((size_t)g * T_ + (t - 1)) * 2 + 0] = s0.mu_s[g];
                out[((size_t)g * T_ + (t - 1)) * 2 + 1] = softp(sg);
            }
            f32x16 tot;
            if (s == 0) {
                #pragma unroll
                for (int r = 0; r < 16; ++r) tot[r] = acc[r] + s0.gtb[r * 256 + m * 64 + lane];
            }
            __syncthreads();
            if (s == 0) {
                #pragma unroll
                for (int r = 0; r < 16; ++r) {
                    int row = m * 32 + (r & 3) + 8 * (r >> 2) + 4 * (lane >> 5);
                    s0.gtb[row * 33 + l31] = tot[r];
                }
            }
            __syncthreads();
            // cell0 + h0 publish (fragment-tiled, full-line) + partial atomics
            u16* hw = h0T + (size_t)pcur * HT_ELEMS;
            const int c_ = g >> 1, half = g & 1;
            #pragma unroll
            for (int p = 0; p < 2; ++p) {
                int id = tid + p * NT;
                int b = id >> 3, j = id & 7;
                float gi = s0.gtb[b * 33 + 4 * j + 0] + s0.bias[4 * j + 0];
                float gf = s0.gtb[b * 33 + 4 * j + 1] + s0.bias[4 * j + 1];
                float gg = s0.gtb[b * 33 + 4 * j + 2] + s0.bias[4 * j + 2];
                float go = s0.gtb[b * 33 + 4 * j + 3] + s0.bias[4 * j + 3];
                if (t > 0 && s0.msk[b]) {       // rank-1 mu-label term (fp32 exact)
                    float mu = s0.mu_s[b];
                    gi += mu * s0.uu[4 * j + 0] + s0.vv[4 * j + 0];
                    gf += mu * s0.uu[4 * j + 1] + s0.vv[4 * j + 1];
                    gg += mu * s0.uu[4 * j + 2] + s0.vv[4 * j + 2];
                    go += mu * s0.uu[4 * j + 3] + s0.vv[4 * j + 3];
                }
                float cold = (p == 0) ? creg0 : creg1;
                float cn = sigm(gf) * cold + sigm(gi) * tanh_(gg);
                float hn = sigm(go) * tanh_(cn);
                if (p == 0) creg0 = cn; else creg1 = cn;
                unsigned hv = f2bf(hn);
                unsigned other = (unsigned)__shfl_xor((int)hv, 1);
                if ((j & 1) == 0) {
                    int l = half * 32 + (b & 31), mb = b >> 5;
                    st_u32(reinterpret_cast<unsigned*>(hw + ((size_t)(c_ * 4 + mb) * 512 + l * 8 + j)),
                           hv | (other << 16));
                }
                float pmu = hn * s0.mwv[j], psg = hn * s0.swv[j];
                pmu += __shfl_xor(pmu, 1); pmu += __shfl_xor(pmu, 2); pmu += __shfl_xor(pmu, 4);
                psg += __shfl_xor(psg, 1); psg += __shfl_xor(psg, 2); psg += __shfl_xor(psg, 4);
                if (j == 0) {
                    atomicAdd(&muacc[(pcur * 128 + b) * 8 + (g & 7)], pmu);
                    atomicAdd(&sgacc[(pcur * 128 + b) * 8 + (g & 7)], psg);
                }
            }
            #pragma unroll
            for (int r = 0; r < 16; ++r) acc[r] = 0.f;
        } else {
            SM1& s1 = smu.b;
            if (t > 0) {   // h1prev GEMM (chunks 64..127)
                const u16* hp = h1T + (size_t)pprev * HT_ELEMS;
                #pragma unroll 8
                for (int c = 0; c < 32; ++c) {
                    int ch = s * 32 + c;
                    bf16x8 a = ld8(hp + ((size_t)ch * 4 + m) * 512 + lane * 8);
                    bf16x8 b = *(const bf16x8*)&s1.bw[(64 + ch) * 512 + lane * 8];
                    acc = mfma32(a, b, acc);
                }
            }
        }
        gbar(actr, relf, blk, ++bc);   // h0(t) + L0 partials at LLC

        // ===================== window 2 =====================
        if (isL0) {
            SM0& s0 = smu.a;
            if (t + 1 < T_) {          // pre-GEMM feat(t+1) + mask-zeroed emb(t+1)
                build_lab(t + 1, true);
                __syncthreads();
                #pragma unroll 6
                for (int c = 0; c < 18; ++c) {
                    int ch = s * 18 + c;
                    bf16x8 a;
                    if (ch < 32) a = ld8(fb2 + (((size_t)(t + 1) * 32 + ch) * 4 + m) * 512 + lane * 8);
                    else         a = *(const bf16x8*)&s0.labf[((ch - 32) * 4 + m) * 512 + lane * 8];
                    bf16x8 b = *(const bf16x8*)&s0.bw[ch * 512 + lane * 8];
                    acc = mfma32(a, b, acc);
                }
            }
        } else {
            SM1& s1 = smu.b;
            if (tid < 8) {             // zero consumed partial slots (race-free here)
                st_f32(&muacc[(pprev * 128 + g) * 8 + tid], 0.f);
                st_f32(&sgacc[(pprev * 128 + g) * 8 + tid], 0.f);
            }
            {   // h0cur GEMM (chunks 0..63)
                const u16* hp = h0T + (size_t)pcur * HT_ELEMS;
                #pragma unroll 8
                for (int c = 0; c < 32; ++c) {
                    int ch = s * 32 + c;
                    bf16x8 a = ld8(hp + ((size_t)ch * 4 + m) * 512 + lane * 8);
                    bf16x8 b = *(const bf16x8*)&s1.bw[ch * 512 + lane * 8];
                    acc = mfma32(a, b, acc);
                }
            }
            if (s == 1) {
                #pragma unroll
                for (int r = 0; r < 16; ++r) s1.gtb[r * 256 + m * 64 + lane] = acc[r];
            }
            __syncthreads();
            f32x16 tot;
            if (s == 0) {
                #pragma unroll
                for (int r = 0; r < 16; ++r) tot[r] = acc[r] + s1.gtb[r * 256 + m * 64 + lane];
            }
            __syncthreads();
            if (s == 0) {
                #pragma unroll
                for (int r = 0; r < 16; ++r) {
                    int row = m * 32 + (r & 3) + 8 * (r >> 2) + 4 * (lane >> 5);
                    s1.gtb[row * 33 + l31] = tot[r];
                }
            }
            __syncthreads();
            // cell1 + h1 publish + partial atomics
            u16* hw = h1T + (size_t)pcur * HT_ELEMS;
            const int c_ = g >> 1, half = g & 1;
            #pragma unroll
            for (int p = 0; p < 2; ++p) {
                int id = tid + p * NT;
                int b = id >> 3, j = id & 7;
                float gi = s1.gtb[b * 33 + 4 * j + 0] + s1.bias[4 * j + 0];
                float gf = s1.gtb[b * 33 + 4 * j + 1] + s1.bias[4 * j + 1];
                float gg = s1.gtb[b * 33 + 4 * j + 2] + s1.bias[4 * j + 2];
                float go = s1.gtb[b * 33 + 4 * j + 3] + s1.bias[4 * j + 3];
                float cold = (p == 0) ? creg0 : creg1;
                float cn = sigm(gf) * cold + sigm(gi) * tanh_(gg);
                float hn = sigm(go) * tanh_(cn);
                if (p == 0) creg0 = cn; else creg1 = cn;
                unsigned hv = f2bf(hn);
                unsigned other = (unsigned)__shfl_xor((int)hv, 1);
                if ((j & 1) == 0) {
                    int l = half * 32 + (b & 31), mb = b >> 5;
                    st_u32(reinterpret_cast<unsigned*>(hw + ((size_t)(c_ * 4 + mb) * 512 + l * 8 + j)),
                           hv | (other << 16));
                }
                float pmu = hn * s1.mwv[j], psg = hn * s1.swv[j];
                pmu += __shfl_xor(pmu, 1); pmu += __shfl_xor(pmu, 2); pmu += __shfl_xor(pmu, 4);
                psg += __shfl_xor(psg, 1); psg += __shfl_xor(psg, 2); psg += __shfl_xor(psg, 4);
                if (j == 0) {
                    atomicAdd(&muacc[(pcur * 128 + b) * 8 + (g & 7)], pmu);
                    atomicAdd(&sgacc[(pcur * 128 + b) * 8 + (g & 7)], psg);
                }
            }
            #pragma unroll
            for (int r = 0; r < 16; ++r) acc[r] = 0.f;
        }
        gbar(actr, relf, blk, ++bc);   // h1(t) + all partials at LLC
    }

    // ---- final output t = T_-1 (parity 1) ----
    if (isL0 && tid == 0) {
        const float4* pm = (const float4*)&muacc[(1 * 128 + g) * 8];
        float4 x = pm[0], y = pm[1];
        float mu = (x.x + x.y) + (x.z + x.w) + (y.x + y.y) + (y.z + y.w) + mub_r;
        const float4* ps = (const float4*)&sgacc[(1 * 128 + g) * 8];
        float4 z = ps[0], u2 = ps[1];
        float sg = (z.x + z.y) + (z.z + z.w) + (u2.x + u2.y) + (u2.z + u2.w) + sgb_r;
        out[((size_t)g * T_ + (T_ - 1)) * 2 + 0] = mu;
        out[((size_t)g * T_ + (T_ - 1)) * 2 + 1] = softp(sg);
    }
}

// ---------------- host ----------------

extern "C" void kernel_launch(void* const* d_in, const int* in_sizes, int n_in,
                              void* d_out, int out_size, void* d_ws, size_t ws_size,
                              hipStream_t stream) {
    const float* feat = (const float*)d_in[0];
    const float* emb  = (const float*)d_in[1];
    const void*  mask = d_in[2];
    const float* Wih0 = (const float*)d_in[3];
    const float* Whh0 = (const float*)d_in[4];
    const float* bih0 = (const float*)d_in[5];
    const float* bhh0 = (const float*)d_in[6];
    const float* Wih1 = (const float*)d_in[7];
    const float* Whh1 = (const float*)d_in[8];
    const float* bih1 = (const float*)d_in[9];
    const float* bhh1 = (const float*)d_in[10];
    const float* Wtgt = (const float*)d_in[11];
    const float* btgt = (const float*)d_in[12];
    const float* muw  = (const float*)d_in[13];
    const float* mub  = (const float*)d_in[14];
    const float* sgw  = (const float*)d_in[15];
    const float* sgb  = (const float*)d_in[16];
    float* out = (float*)d_out;
    char* ws = (char*)d_ws;
    (void)in_sizes; (void)n_in; (void)out_size; (void)ws_size;

    size_t off = 0;
    auto alloc = [&](size_t bytes) {
        size_t o = off;
        off = (off + bytes + 255) & ~(size_t)255;
        return o;
    };
    size_t o_flags = alloc(256);
    size_t o_actr  = alloc(8 * 32 * 4);
    size_t o_rel   = alloc(256);
    size_t o_muacc = alloc((size_t)2 * 128 * 8 * 4);
    size_t o_sgacc = alloc((size_t)2 * 128 * 8 * 4);
    size_t zero_end = off;
    size_t o_h0    = alloc((size_t)2 * HT_ELEMS * 2);
    size_t o_h1    = alloc((size_t)2 * HT_ELEMS * 2);
    size_t o_fb2   = alloc((size_t)T_ * 32 * 4 * 512 * 2);

    int*      flags = (int*)(ws + o_flags);
    unsigned* actr  = (unsigned*)(ws + o_actr);
    unsigned* relf  = (unsigned*)(ws + o_rel);
    float*    muacc = (float*)(ws + o_muacc);
    float*    sgacc = (float*)(ws + o_sgacc);
    u16*      h0    = (u16*)(ws + o_h0);
    u16*      h1    = (u16*)(ws + o_h1);
    u16*      fb2   = (u16*)(ws + o_fb2);

    hipMemsetAsync(ws, 0, zero_end, stream);
    detect_mask<<<20, 256, 0, stream>>>((const unsigned*)mask, flags);
    featconv<<<10240, 256, 0, stream>>>(feat, fb2);

    persist<<<NBLK, NT, 0, stream>>>(
        fb2, emb, mask, flags,
        Wih0, Whh0, bih0, bhh0,
        Wih1, Whh1, bih1, bhh1,
        Wtgt, btgt, muw, mub, sgw, sgb,
        h0, h1, muacc, sgacc, actr, relf, out);
}